// Round 10
// baseline (60045.990 us; speedup 1.0000x reference)
//
#include <hip/hip_runtime.h>

#define B_ 32
#define T_FULL 4096
#define EMB_ 256
#define XD_ 768
#define H_ 896
#define G3_ 2688
#define O_ 512
#define NWG_SCAN 14
#define THR_SCAN 768

typedef __attribute__((ext_vector_type(8))) short bf16x8;
typedef __attribute__((ext_vector_type(4))) float f32x4;
typedef __attribute__((ext_vector_type(16))) float f32x16;

__device__ __forceinline__ f32x4 mfma16(bf16x8 a, bf16x8 b, f32x4 c) {
  return __builtin_amdgcn_mfma_f32_16x16x32_bf16(a, b, c, 0, 0, 0);
}
__device__ __forceinline__ f32x16 mfma32(bf16x8 a, bf16x8 b, f32x16 c) {
  return __builtin_amdgcn_mfma_f32_32x32x16_bf16(a, b, c, 0, 0, 0);
}

__device__ __forceinline__ unsigned short f2bf(float x) {
  union { float f; unsigned u; } v; v.f = x;
  unsigned r = v.u + 0x7fffu + ((v.u >> 16) & 1u);
  return (unsigned short)(r >> 16);
}
__device__ __forceinline__ float bf2f(unsigned short h) {
  union { float f; unsigned u; } v; v.u = ((unsigned)h) << 16;
  return v.f;
}

__device__ __forceinline__ unsigned long long aload64(const unsigned long long* p) {
  return __hip_atomic_load((unsigned long long*)p, __ATOMIC_RELAXED, __HIP_MEMORY_SCOPE_AGENT);
}
__device__ __forceinline__ unsigned aload32(const unsigned* p) {
  return __hip_atomic_load((unsigned*)p, __ATOMIC_RELAXED, __HIP_MEMORY_SCOPE_AGENT);
}
__device__ __forceinline__ void astore32(unsigned* p, unsigned v) {
  __hip_atomic_store(p, v, __ATOMIC_RELAXED, __HIP_MEMORY_SCOPE_AGENT);
}
__device__ __forceinline__ void astore64(unsigned long long* p, unsigned long long v) {
  __hip_atomic_store(p, v, __ATOMIC_RELAXED, __HIP_MEMORY_SCOPE_AGENT);
}

// swizzled h layout: row = batch (0..31), 1792 B/row; granule (16B) index g of byte
// col cb: g' = (g & ~15) | ((g & 15) ^ (row & 15)); planes hi/lo offset 57344.
__device__ __forceinline__ int hswz(int row, int cb) {
  const int g = cb >> 4;
  const int gs = (g & ~15) | ((g & 15) ^ (row & 15));
  return row * 1792 + (gs << 4) + (cb & 15);
}

__global__ __launch_bounds__(256) void cvt_bf16(const float* __restrict__ in,
                                                unsigned short* __restrict__ out, int n) {
  for (int i = blockIdx.x * 256 + threadIdx.x; i < n; i += gridDim.x * 256)
    out[i] = f2bf(in[i]);
}

// VAR: 0 = gates (A = concat(emb[sample], icnd) built on the fly, out fp32 [row][2688])
//      1 = fc1   (A = ornn bf16, out bf16 relu [row][896])
//      2 = fc2   (A = hidden bf16, out fp32 scattered to d_out [b][t][512])
template<int VAR>
__global__ __launch_bounds__(256) void gemm_bf16(
    const unsigned short* __restrict__ A,
    const int* __restrict__ sample,
    const float* __restrict__ icnd,
    const unsigned short* __restrict__ embb,
    const unsigned short* __restrict__ W,
    const float* __restrict__ bias,
    float* __restrict__ outf,
    unsigned short* __restrict__ outb,
    int t0) {
  constexpr int K = (VAR == 0) ? XD_ : H_;
  constexpr int N = (VAR == 0) ? G3_ : (VAR == 1 ? H_ : O_);
  constexpr int LDT = 48;
  __shared__ __align__(16) unsigned short Asl[128 * LDT];
  __shared__ __align__(16) unsigned short Bsl[128 * LDT];
  const int tid = threadIdx.x;
  const int rowBase = blockIdx.y * 128, colBase = blockIdx.x * 128;
  const int lane = tid & 63, wid = tid >> 6;
  const int wm = wid >> 1, wn = wid & 1;
  const int lr = lane & 15, lk = lane >> 4;
  const f32x4 fzero = {0.f, 0.f, 0.f, 0.f};
  f32x4 acc[4][4];
#pragma unroll
  for (int i = 0; i < 4; ++i)
#pragma unroll
    for (int j = 0; j < 4; ++j) acc[i][j] = fzero;

  for (int k0 = 0; k0 < K; k0 += 32) {
#pragma unroll
    for (int s = 0; s < 2; ++s) {
      const int seg = tid + s * 256;           // 512 segments of 8 elems
      const int r = seg >> 2, kg = (seg & 3) * 8;
      const int kk = k0 + kg;
      bf16x8 va;
      if (VAR == 0) {
        const int rowG = rowBase + r;
        const int b = rowG & 31, t = t0 + (rowG >> 5);
        if (kk < EMB_) {
          const int e = sample[b * T_FULL + t];
          va = *(const bf16x8*)(embb + e * EMB_ + kk);
        } else {
          const float* p = icnd + ((size_t)(b * T_FULL + t)) * 512 + (kk - EMB_);
          const float4 f0 = *(const float4*)p;
          const float4 f1 = *(const float4*)(p + 4);
          va[0] = (short)f2bf(f0.x); va[1] = (short)f2bf(f0.y);
          va[2] = (short)f2bf(f0.z); va[3] = (short)f2bf(f0.w);
          va[4] = (short)f2bf(f1.x); va[5] = (short)f2bf(f1.y);
          va[6] = (short)f2bf(f1.z); va[7] = (short)f2bf(f1.w);
        }
      } else {
        va = *(const bf16x8*)(A + (size_t)(rowBase + r) * K + kk);
      }
      *(bf16x8*)(Asl + r * LDT + kg) = va;
      *(bf16x8*)(Bsl + r * LDT + kg) = *(const bf16x8*)(W + (size_t)(colBase + r) * K + kk);
    }
    __syncthreads();
    bf16x8 af[4], bfr[4];
#pragma unroll
    for (int mt = 0; mt < 4; ++mt)
      af[mt] = *(const bf16x8*)(Asl + (wm * 64 + mt * 16 + lr) * LDT + lk * 8);
#pragma unroll
    for (int nt = 0; nt < 4; ++nt)
      bfr[nt] = *(const bf16x8*)(Bsl + (wn * 64 + nt * 16 + lr) * LDT + lk * 8);
#pragma unroll
    for (int mt = 0; mt < 4; ++mt)
#pragma unroll
      for (int nt = 0; nt < 4; ++nt) acc[mt][nt] = mfma16(af[mt], bfr[nt], acc[mt][nt]);
    __syncthreads();
  }

#pragma unroll
  for (int mt = 0; mt < 4; ++mt) {
#pragma unroll
    for (int nt = 0; nt < 4; ++nt) {
      const int colG = colBase + wn * 64 + nt * 16 + lr;
      const float bv = bias[colG];
#pragma unroll
      for (int r = 0; r < 4; ++r) {
        const int rowG = rowBase + wm * 64 + mt * 16 + lk * 4 + r;
        const float v = acc[mt][nt][r] + bv;
        if (VAR == 0) {
          outf[(size_t)rowG * N + colG] = v;
        } else if (VAR == 1) {
          outb[(size_t)rowG * N + colG] = f2bf(fmaxf(v, 0.f));
        } else {
          const int b = rowG & 31, t = t0 + (rowG >> 5);
          outf[((size_t)(b * T_FULL + t)) * O_ + colG] = v;
        }
      }
    }
  }
}

// Persistent GRU scan v10: v8 sync structure, HALF the sync domain.
// 14 WGs x 768 threads, 64 units per WG.
// P1: identity-copy gather (two register batches) of full h -> swizzled hst.
// P2: 6 MFMA waves = 3 strips x 2 unit-tiles, full-K sweep (56 iters, mfma32);
//     weights streamed from L2; single gh slot [192][32], plain stores.
// P3: 512 threads x 4 units cell; agent-scope h stores (pre-swizzled layout).
// P4: drain, arrival slot, wave0 lane-parallel spin poll (no sleep).
__global__ __launch_bounds__(THR_SCAN, 3) void scan_gru(
    const float* __restrict__ gates,          // [Tc*32][2688] fp32
    const unsigned short* __restrict__ whh,   // [2688][896] bf16
    const float* __restrict__ bhh,            // [2688]
    unsigned long long* __restrict__ hbuf,    // [2][114688 B] swizzled h (hi|lo planes)
    unsigned short* __restrict__ ornn,        // [Tc*32][896] bf16
    unsigned int* __restrict__ arr,           // arrival slots (zeroed per call)
    int t0, int Tc) {
  __shared__ __align__(16) char hst[114688];  // identical layout to hbuf plane
  __shared__ float gh2f[192 * 32];            // [strip*64 + unit][col] partials
  const int tid = threadIdx.x;
  const int j0 = blockIdx.x * 64;
  const int lane = tid & 63, wid = tid >> 6;
  const int l31 = lane & 31, lhi = lane >> 5;
  const int eb = tid >> 4, ec = (tid & 15) * 4;  // elementwise identity (tid<512)

  // ---- persistent: bias + fp32 h state for own 4 units ----
  float bhr[4], bhz[4], bhn[4], hown[4];
#pragma unroll
  for (int e = 0; e < 4; ++e) { bhr[e] = 0.f; bhz[e] = 0.f; bhn[e] = 0.f; hown[e] = 0.f; }
  if (tid < 512) {
    const int j = j0 + ec;
    const float4 br = *(const float4*)(bhh + j);
    const float4 bz = *(const float4*)(bhh + H_ + j);
    const float4 bn = *(const float4*)(bhh + 2 * H_ + j);
    bhr[0] = br.x; bhr[1] = br.y; bhr[2] = br.z; bhr[3] = br.w;
    bhz[0] = bz.x; bhz[1] = bz.y; bhz[2] = bz.z; bhz[3] = bz.w;
    bhn[0] = bn.x; bhn[1] = bn.y; bhn[2] = bn.z; bhn[3] = bn.w;
    const int rb0 = (t0 + 1) & 1;
    const char* hb = (const char*)hbuf + rb0 * 114688;
    const int off = hswz(eb, 2 * j);
    const unsigned long long hi4 = aload64((const unsigned long long*)(hb + off));
    const unsigned long long lo4 = aload64((const unsigned long long*)(hb + off + 57344));
#pragma unroll
    for (int e = 0; e < 4; ++e) {
      hown[e] = bf2f((unsigned short)((hi4 >> (16 * e)) & 0xffff)) +
                bf2f((unsigned short)((lo4 >> (16 * e)) & 0xffff));
    }
  }

  for (int tl = 0; tl < Tc; ++tl) {
    const int t = t0 + tl;
    const int rb = (t + 1) & 1, wb = t & 1;

    // ---- P1: gates prefetch + identity-copy register-batched gather ----
    float4 pxr = {0.f, 0.f, 0.f, 0.f}, pxz = {0.f, 0.f, 0.f, 0.f}, pxn = {0.f, 0.f, 0.f, 0.f};
    if (tid < 512) {
      const float* gx = gates + ((size_t)tl * 32 + eb) * G3_;
      pxr = *(const float4*)(gx + j0 + ec);
      pxz = *(const float4*)(gx + H_ + j0 + ec);
      pxn = *(const float4*)(gx + 2 * H_ + j0 + ec);
    }
    {
      const unsigned long long* src = hbuf + (size_t)rb * 14336;
      unsigned long long rg[10];
#pragma unroll
      for (int k = 0; k < 10; ++k) rg[k] = aload64(src + tid + k * 768);
      __builtin_amdgcn_sched_barrier(0);
#pragma unroll
      for (int k = 0; k < 10; ++k)
        *(unsigned long long*)(hst + (size_t)(tid + k * 768) * 8) = rg[k];
      unsigned long long rg2[9];
#pragma unroll
      for (int k = 0; k < 9; ++k) {
        const int i = tid + (10 + k) * 768;
        rg2[k] = (i < 14336) ? aload64(src + i) : 0ull;
      }
      __builtin_amdgcn_sched_barrier(0);
#pragma unroll
      for (int k = 0; k < 9; ++k) {
        const int i = tid + (10 + k) * 768;
        if (i < 14336) *(unsigned long long*)(hst + (size_t)i * 8) = rg2[k];
      }
    }
    __syncthreads();

    // ---- P2: 6 waves (3 strips x 2 unit-tiles), full-K mfma32, plain stores ----
    if (wid < 6) {
      const int s2 = wid >> 1, ut = wid & 1;
      const unsigned short* wp =
          whh + (size_t)(s2 * H_ + j0 + ut * 32 + l31) * H_ + lhi * 8;
      f32x16 acc;
#pragma unroll
      for (int r = 0; r < 16; ++r) acc[r] = 0.f;
#pragma unroll
      for (int i = 0; i < 56; ++i) {
        const int g = i * 2 + lhi;
        const int gs = (g & ~15) | ((g & 15) ^ (l31 & 15));
        const int off = l31 * 1792 + (gs << 4);
        const bf16x8 bh = *(const bf16x8*)(hst + off);
        const bf16x8 bl = *(const bf16x8*)(hst + 57344 + off);
        const bf16x8 bw = *(const bf16x8*)(wp + i * 16);
        acc = mfma32(bw, bh, acc);
        acc = mfma32(bw, bl, acc);
      }
#pragma unroll
      for (int r = 0; r < 16; ++r) {
        const int rowD = (r & 3) + 8 * (r >> 2) + 4 * lhi;
        gh2f[(s2 * 64 + ut * 32 + rowD) * 32 + (l31 ^ rowD)] = acc[r];
      }
    }
    __syncthreads();

    // ---- P3: elementwise GRU cell (4 units/thread) + h stores + ornn ----
    if (tid < 512) {
      unsigned long long hi4 = 0, lo4 = 0;
      const float px_r[4] = {pxr.x, pxr.y, pxr.z, pxr.w};
      const float px_z[4] = {pxz.x, pxz.y, pxz.z, pxz.w};
      const float px_n[4] = {pxn.x, pxn.y, pxn.z, pxn.w};
#pragma unroll
      for (int e = 0; e < 4; ++e) {
        const int uu = ec + e;
        const int col = eb ^ (uu & 31);
        const float ghr = gh2f[uu * 32 + col] + bhr[e];
        const float ghz = gh2f[(64 + uu) * 32 + col] + bhz[e];
        const float ghn = gh2f[(128 + uu) * 32 + col] + bhn[e];
        const float r0 = 1.f / (1.f + __expf(-(px_r[e] + ghr)));
        const float z0 = 1.f / (1.f + __expf(-(px_z[e] + ghz)));
        const float e0 = __expf(2.f * (px_n[e] + r0 * ghn));
        const float n0 = 1.f - 2.f / (e0 + 1.f);
        const float hnew = (1.f - z0) * n0 + z0 * hown[e];
        hown[e] = hnew;
        const unsigned short h0 = f2bf(hnew);
        const unsigned short l0 = f2bf(hnew - bf2f(h0));
        hi4 |= ((unsigned long long)h0) << (16 * e);
        lo4 |= ((unsigned long long)l0) << (16 * e);
      }
      char* hb = (char*)hbuf + wb * 114688;
      const int off = hswz(eb, 2 * (j0 + ec));
      astore64((unsigned long long*)(hb + off), hi4);
      astore64((unsigned long long*)(hb + off + 57344), lo4);
      *(unsigned long long*)(ornn + ((size_t)tl * 32 + eb) * H_ + j0 + ec) = hi4;
    }

    // ---- P4: drain, arrive, lane-parallel spin poll ----
    asm volatile("s_waitcnt vmcnt(0)" ::: "memory");
    __syncthreads();
    const unsigned tgt = (unsigned)(t + 1);
    if (tid == 0) astore32(arr + blockIdx.x, tgt);
    if (wid == 0) {
      for (;;) {
        const unsigned v = (lane < NWG_SCAN) ? aload32(arr + lane) : tgt;
        if (__all(v >= tgt)) break;
      }
    }
    __syncthreads();
  }
}

extern "C" void kernel_launch(void* const* d_in, const int* in_sizes, int n_in,
                              void* d_out, int out_size, void* d_ws, size_t ws_size,
                              hipStream_t stream) {
  (void)in_sizes; (void)n_in; (void)out_size;
  const int* sample = (const int*)d_in[0];
  const float* icnd = (const float*)d_in[1];
  const float* emb = (const float*)d_in[2];
  const float* wih = (const float*)d_in[3];
  const float* whh = (const float*)d_in[4];
  const float* bih = (const float*)d_in[5];
  const float* bhh = (const float*)d_in[6];
  const float* fc1w = (const float*)d_in[7];
  const float* fc1b = (const float*)d_in[8];
  const float* fc2w = (const float*)d_in[9];
  const float* fc2b = (const float*)d_in[10];
  float* out = (float*)d_out;
  char* ws = (char*)d_ws;

  size_t off = 0;
  auto alloc = [&](size_t bytes) {
    size_t o = off;
    off = (off + bytes + 255) & ~(size_t)255;
    return o;
  };
  const size_t o_arr = alloc(256);
  const size_t o_h = alloc((size_t)2 * 114688);  // swizzled h, 2 time slots
  const size_t zero_end = off;
  const size_t o_emb = alloc((size_t)O_ * EMB_ * 2);
  const size_t o_wih = alloc((size_t)G3_ * XD_ * 2);
  const size_t o_whh = alloc((size_t)G3_ * H_ * 2);
  const size_t o_f1w = alloc((size_t)H_ * H_ * 2);
  const size_t o_f2w = alloc((size_t)O_ * H_ * 2);
  const size_t head = off;

  int Tc = 512;
  while (Tc > 8) {
    size_t need = head + (size_t)Tc * 32 * G3_ * 4 + 2 * ((size_t)Tc * 32 * H_ * 2) + 4096;
    if (need <= ws_size) break;
    Tc >>= 1;
  }
  const size_t o_gat = alloc((size_t)Tc * 32 * G3_ * 4);
  const size_t o_orn = alloc((size_t)Tc * 32 * H_ * 2);
  const size_t o_hid = alloc((size_t)Tc * 32 * H_ * 2);
  (void)o_gat; (void)o_orn; (void)o_hid;

  unsigned short* embb = (unsigned short*)(ws + o_emb);
  unsigned short* wihb = (unsigned short*)(ws + o_wih);
  unsigned short* whhb = (unsigned short*)(ws + o_whh);
  unsigned short* f1wb = (unsigned short*)(ws + o_f1w);
  unsigned short* f2wb = (unsigned short*)(ws + o_f2w);
  float* gat = (float*)(ws + o_gat);
  unsigned short* orn = (unsigned short*)(ws + o_orn);
  unsigned short* hid = (unsigned short*)(ws + o_hid);
  unsigned long long* hbuf = (unsigned long long*)(ws + o_h);
  unsigned int* arr = (unsigned int*)(ws + o_arr);

  // zero arrival slots + h state (required every call: deterministic replays)
  (void)hipMemsetAsync(ws, 0, zero_end, stream);

  cvt_bf16<<<512, 256, 0, stream>>>(emb, embb, O_ * EMB_);
  cvt_bf16<<<1024, 256, 0, stream>>>(wih, wihb, G3_ * XD_);
  cvt_bf16<<<1024, 256, 0, stream>>>(whh, whhb, G3_ * H_);
  cvt_bf16<<<512, 256, 0, stream>>>(fc1w, f1wb, H_ * H_);
  cvt_bf16<<<512, 256, 0, stream>>>(fc2w, f2wb, O_ * H_);

  const int nch = T_FULL / Tc;
  const int M = Tc * 32;
  for (int c = 0; c < nch; ++c) {
    const int t0 = c * Tc;
    gemm_bf16<0><<<dim3(G3_ / 128, M / 128), 256, 0, stream>>>(
        nullptr, sample, icnd, embb, wihb, bih, gat, nullptr, t0);
    scan_gru<<<NWG_SCAN, THR_SCAN, 0, stream>>>(gat, whhb, bhh, hbuf, orn, arr, t0, Tc);
    gemm_bf16<1><<<dim3(H_ / 128, M / 128), 256, 0, stream>>>(
        orn, nullptr, nullptr, nullptr, f1wb, fc1b, nullptr, hid, t0);
    gemm_bf16<2><<<dim3(O_ / 128, M / 128), 256, 0, stream>>>(
        hid, nullptr, nullptr, nullptr, f2wb, fc2b, out, nullptr, t0);
  }
}

// Round 11
// 41761.838 us; speedup vs baseline: 1.4378x; 1.4378x over previous
//
#include <hip/hip_runtime.h>

#define B_ 32
#define T_FULL 4096
#define EMB_ 256
#define XD_ 768
#define H_ 896
#define G3_ 2688
#define O_ 512
#define NWG_SCAN 28
#define THR_SCAN 768

typedef __attribute__((ext_vector_type(8))) short bf16x8;
typedef __attribute__((ext_vector_type(4))) float f32x4;
typedef __attribute__((ext_vector_type(16))) float f32x16;

__device__ __forceinline__ f32x4 mfma16(bf16x8 a, bf16x8 b, f32x4 c) {
  return __builtin_amdgcn_mfma_f32_16x16x32_bf16(a, b, c, 0, 0, 0);
}
__device__ __forceinline__ f32x16 mfma32(bf16x8 a, bf16x8 b, f32x16 c) {
  return __builtin_amdgcn_mfma_f32_32x32x16_bf16(a, b, c, 0, 0, 0);
}

__device__ __forceinline__ unsigned short f2bf(float x) {
  union { float f; unsigned u; } v; v.f = x;
  unsigned r = v.u + 0x7fffu + ((v.u >> 16) & 1u);
  return (unsigned short)(r >> 16);
}
__device__ __forceinline__ float bf2f(unsigned short h) {
  union { float f; unsigned u; } v; v.u = ((unsigned)h) << 16;
  return v.f;
}

__device__ __forceinline__ unsigned long long aload64(const unsigned long long* p) {
  return __hip_atomic_load((unsigned long long*)p, __ATOMIC_RELAXED, __HIP_MEMORY_SCOPE_AGENT);
}
__device__ __forceinline__ unsigned aload32(const unsigned* p) {
  return __hip_atomic_load((unsigned*)p, __ATOMIC_RELAXED, __HIP_MEMORY_SCOPE_AGENT);
}
__device__ __forceinline__ void astore32(unsigned* p, unsigned v) {
  __hip_atomic_store(p, v, __ATOMIC_RELAXED, __HIP_MEMORY_SCOPE_AGENT);
}

// swizzled h layout: row = batch (0..31), 1792 B/row; granule (16B) index g of byte
// col cb: g' = (g & ~15) | ((g & 15) ^ (row & 15)); planes hi/lo offset 57344.
__device__ __forceinline__ int hswz(int row, int cb) {
  const int g = cb >> 4;
  const int gs = (g & ~15) | ((g & 15) ^ (row & 15));
  return row * 1792 + (gs << 4) + (cb & 15);
}

__global__ __launch_bounds__(256) void cvt_bf16(const float* __restrict__ in,
                                                unsigned short* __restrict__ out, int n) {
  for (int i = blockIdx.x * 256 + threadIdx.x; i < n; i += gridDim.x * 256)
    out[i] = f2bf(in[i]);
}

// VAR: 0 = gates (A = concat(emb[sample], icnd) built on the fly, out fp32 [row][2688])
//      1 = fc1   (A = ornn bf16, out bf16 relu [row][896])
//      2 = fc2   (A = hidden bf16, out fp32 scattered to d_out [b][t][512])
template<int VAR>
__global__ __launch_bounds__(256) void gemm_bf16(
    const unsigned short* __restrict__ A,
    const int* __restrict__ sample,
    const float* __restrict__ icnd,
    const unsigned short* __restrict__ embb,
    const unsigned short* __restrict__ W,
    const float* __restrict__ bias,
    float* __restrict__ outf,
    unsigned short* __restrict__ outb,
    int t0) {
  constexpr int K = (VAR == 0) ? XD_ : H_;
  constexpr int N = (VAR == 0) ? G3_ : (VAR == 1 ? H_ : O_);
  constexpr int LDT = 48;
  __shared__ __align__(16) unsigned short Asl[128 * LDT];
  __shared__ __align__(16) unsigned short Bsl[128 * LDT];
  const int tid = threadIdx.x;
  const int rowBase = blockIdx.y * 128, colBase = blockIdx.x * 128;
  const int lane = tid & 63, wid = tid >> 6;
  const int wm = wid >> 1, wn = wid & 1;
  const int lr = lane & 15, lk = lane >> 4;
  const f32x4 fzero = {0.f, 0.f, 0.f, 0.f};
  f32x4 acc[4][4];
#pragma unroll
  for (int i = 0; i < 4; ++i)
#pragma unroll
    for (int j = 0; j < 4; ++j) acc[i][j] = fzero;

  for (int k0 = 0; k0 < K; k0 += 32) {
#pragma unroll
    for (int s = 0; s < 2; ++s) {
      const int seg = tid + s * 256;           // 512 segments of 8 elems
      const int r = seg >> 2, kg = (seg & 3) * 8;
      const int kk = k0 + kg;
      bf16x8 va;
      if (VAR == 0) {
        const int rowG = rowBase + r;
        const int b = rowG & 31, t = t0 + (rowG >> 5);
        if (kk < EMB_) {
          const int e = sample[b * T_FULL + t];
          va = *(const bf16x8*)(embb + e * EMB_ + kk);
        } else {
          const float* p = icnd + ((size_t)(b * T_FULL + t)) * 512 + (kk - EMB_);
          const float4 f0 = *(const float4*)p;
          const float4 f1 = *(const float4*)(p + 4);
          va[0] = (short)f2bf(f0.x); va[1] = (short)f2bf(f0.y);
          va[2] = (short)f2bf(f0.z); va[3] = (short)f2bf(f0.w);
          va[4] = (short)f2bf(f1.x); va[5] = (short)f2bf(f1.y);
          va[6] = (short)f2bf(f1.z); va[7] = (short)f2bf(f1.w);
        }
      } else {
        va = *(const bf16x8*)(A + (size_t)(rowBase + r) * K + kk);
      }
      *(bf16x8*)(Asl + r * LDT + kg) = va;
      *(bf16x8*)(Bsl + r * LDT + kg) = *(const bf16x8*)(W + (size_t)(colBase + r) * K + kk);
    }
    __syncthreads();
    bf16x8 af[4], bfr[4];
#pragma unroll
    for (int mt = 0; mt < 4; ++mt)
      af[mt] = *(const bf16x8*)(Asl + (wm * 64 + mt * 16 + lr) * LDT + lk * 8);
#pragma unroll
    for (int nt = 0; nt < 4; ++nt)
      bfr[nt] = *(const bf16x8*)(Bsl + (wn * 64 + nt * 16 + lr) * LDT + lk * 8);
#pragma unroll
    for (int mt = 0; mt < 4; ++mt)
#pragma unroll
      for (int nt = 0; nt < 4; ++nt) acc[mt][nt] = mfma16(af[mt], bfr[nt], acc[mt][nt]);
    __syncthreads();
  }

#pragma unroll
  for (int mt = 0; mt < 4; ++mt) {
#pragma unroll
    for (int nt = 0; nt < 4; ++nt) {
      const int colG = colBase + wn * 64 + nt * 16 + lr;
      const float bv = bias[colG];
#pragma unroll
      for (int r = 0; r < 4; ++r) {
        const int rowG = rowBase + wm * 64 + mt * 16 + lk * 4 + r;
        const float v = acc[mt][nt][r] + bv;
        if (VAR == 0) {
          outf[(size_t)rowG * N + colG] = v;
        } else if (VAR == 1) {
          outb[(size_t)rowG * N + colG] = f2bf(fmaxf(v, 0.f));
        } else {
          const int b = rowG & 31, t = t0 + (rowG >> 5);
          outf[((size_t)(b * T_FULL + t)) * O_ + colG] = v;
        }
      }
    }
  }
}

// Persistent GRU scan v11 = v8 + (a) 4-way accumulator split in P2 (chain 56 -> 14,
// forces register budget -> load lookahead) and (b) ornn HBM store moved off the
// drain path (posted under the poll shadow).
__global__ __launch_bounds__(THR_SCAN, 3) void scan_gru(
    const float* __restrict__ gates,          // [Tc*32][2688] fp32
    const unsigned short* __restrict__ whh,   // [2688][896] bf16
    const float* __restrict__ bhh,            // [2688]
    unsigned long long* __restrict__ hbuf,    // [2][114688 B] swizzled h (hi|lo planes)
    unsigned short* __restrict__ ornn,        // [Tc*32][896] bf16
    unsigned int* __restrict__ arr,           // arrival slots (zeroed per call)
    int t0, int Tc) {
  __shared__ __align__(16) char hst[114688];  // identical layout to hbuf plane
  __shared__ float gh2f[2 * 96 * 32];         // [kh][96 rows][32 cols] partials
  const int tid = threadIdx.x;
  const int j0 = blockIdx.x * 32;
  const int lane = tid & 63, wid = tid >> 6;
  const int l31 = lane & 31, lhi = lane >> 5;
  const int eb = tid >> 4, ec = (tid & 15) * 2;  // elementwise identity (tid<512)

  // ---- persistent: bias + fp32 h state for own 2 units ----
  float bh0 = 0.f, bh1 = 0.f, bh2 = 0.f, bh3 = 0.f, bh4 = 0.f, bh5 = 0.f;
  float hown0 = 0.f, hown1 = 0.f;
  if (tid < 512) {
    const int j = j0 + ec;
    bh0 = bhh[j];          bh1 = bhh[j + 1];
    bh2 = bhh[H_ + j];     bh3 = bhh[H_ + j + 1];
    bh4 = bhh[2 * H_ + j]; bh5 = bhh[2 * H_ + j + 1];
    const int rb0 = (t0 + 1) & 1;
    const char* hb = (const char*)hbuf + rb0 * 114688;
    const int off = hswz(eb, 2 * j);
    const unsigned hi01 = aload32((const unsigned*)(hb + off));
    const unsigned lo01 = aload32((const unsigned*)(hb + off + 57344));
    hown0 = bf2f((unsigned short)(hi01 & 0xffff)) + bf2f((unsigned short)(lo01 & 0xffff));
    hown1 = bf2f((unsigned short)(hi01 >> 16)) + bf2f((unsigned short)(lo01 >> 16));
  }

  for (int tl = 0; tl < Tc; ++tl) {
    const int t = t0 + tl;
    const int rb = (t + 1) & 1, wb = t & 1;

    // ---- P1: gates prefetch + identity-copy register-batched gather ----
    float2 pxr = {0.f, 0.f}, pxz = {0.f, 0.f}, pxn = {0.f, 0.f};
    if (tid < 512) {
      const float* gx = gates + ((size_t)tl * 32 + eb) * G3_;
      pxr = *(const float2*)(gx + j0 + ec);
      pxz = *(const float2*)(gx + H_ + j0 + ec);
      pxn = *(const float2*)(gx + 2 * H_ + j0 + ec);
    }
    {
      const unsigned long long* src = hbuf + (size_t)rb * 14336;
      unsigned long long rg[10];
#pragma unroll
      for (int k = 0; k < 10; ++k) rg[k] = aload64(src + tid + k * 768);
      __builtin_amdgcn_sched_barrier(0);
#pragma unroll
      for (int k = 0; k < 10; ++k)
        *(unsigned long long*)(hst + (size_t)(tid + k * 768) * 8) = rg[k];
      unsigned long long rg2[9];
#pragma unroll
      for (int k = 0; k < 9; ++k) {
        const int i = tid + (10 + k) * 768;
        rg2[k] = (i < 14336) ? aload64(src + i) : 0ull;
      }
      __builtin_amdgcn_sched_barrier(0);
#pragma unroll
      for (int k = 0; k < 9; ++k) {
        const int i = tid + (10 + k) * 768;
        if (i < 14336) *(unsigned long long*)(hst + (size_t)i * 8) = rg2[k];
      }
    }
    __syncthreads();

    // ---- P2: 6 waves (3 strips x 2 K-halves), 4-way acc split, disjoint stores ----
    if (wid < 6) {
      const int s2 = wid >> 1, kh = wid & 1;
      const unsigned short* wp =
          whh + (size_t)(s2 * H_ + j0 + l31) * H_ + kh * 448 + lhi * 8;
      f32x16 ah0, ah1, al0, al1;
#pragma unroll
      for (int r = 0; r < 16; ++r) { ah0[r] = 0.f; ah1[r] = 0.f; al0[r] = 0.f; al1[r] = 0.f; }
#pragma unroll
      for (int i = 0; i < 14; ++i) {
        {
          const int g = (kh * 28 + i) * 2 + lhi;
          const int gs = (g & ~15) | ((g & 15) ^ (l31 & 15));
          const int off = l31 * 1792 + (gs << 4);
          const bf16x8 bh = *(const bf16x8*)(hst + off);
          const bf16x8 bl = *(const bf16x8*)(hst + 57344 + off);
          const bf16x8 bw = *(const bf16x8*)(wp + i * 16);
          ah0 = mfma32(bw, bh, ah0);
          al0 = mfma32(bw, bl, al0);
        }
        {
          const int i2 = i + 14;
          const int g = (kh * 28 + i2) * 2 + lhi;
          const int gs = (g & ~15) | ((g & 15) ^ (l31 & 15));
          const int off = l31 * 1792 + (gs << 4);
          const bf16x8 bh = *(const bf16x8*)(hst + off);
          const bf16x8 bl = *(const bf16x8*)(hst + 57344 + off);
          const bf16x8 bw = *(const bf16x8*)(wp + i2 * 16);
          ah1 = mfma32(bw, bh, ah1);
          al1 = mfma32(bw, bl, al1);
        }
      }
#pragma unroll
      for (int r = 0; r < 16; ++r) {
        const int rowD = (r & 3) + 8 * (r >> 2) + 4 * lhi;
        gh2f[(kh * 96 + s2 * 32 + rowD) * 32 + (l31 ^ rowD)] =
            (ah0[r] + ah1[r]) + (al0[r] + al1[r]);
      }
    }
    __syncthreads();

    // ---- P3: elementwise GRU cell (merge 2 slots) + swizzled h stores ----
    unsigned orn_val = 0;
    if (tid < 512) {
      const int b0 = (0 * 32 + ec) * 32, b1 = (1 * 32 + ec) * 32, b2 = (2 * 32 + ec) * 32;
      const int c0 = eb ^ ec, c1 = eb ^ (ec + 1);
      const float ghr0 = gh2f[b0 + c0] + gh2f[3072 + b0 + c0] + bh0;
      const float ghr1 = gh2f[b0 + 32 + c1] + gh2f[3072 + b0 + 32 + c1] + bh1;
      const float ghz0 = gh2f[b1 + c0] + gh2f[3072 + b1 + c0] + bh2;
      const float ghz1 = gh2f[b1 + 32 + c1] + gh2f[3072 + b1 + 32 + c1] + bh3;
      const float ghn0 = gh2f[b2 + c0] + gh2f[3072 + b2 + c0] + bh4;
      const float ghn1 = gh2f[b2 + 32 + c1] + gh2f[3072 + b2 + 32 + c1] + bh5;
      const float r0 = 1.f / (1.f + __expf(-(pxr.x + ghr0)));
      const float r1 = 1.f / (1.f + __expf(-(pxr.y + ghr1)));
      const float z0 = 1.f / (1.f + __expf(-(pxz.x + ghz0)));
      const float z1 = 1.f / (1.f + __expf(-(pxz.y + ghz1)));
      const float e0 = __expf(2.f * (pxn.x + r0 * ghn0));
      const float e1 = __expf(2.f * (pxn.y + r1 * ghn1));
      const float n0 = 1.f - 2.f / (e0 + 1.f);
      const float n1 = 1.f - 2.f / (e1 + 1.f);
      hown0 = (1.f - z0) * n0 + z0 * hown0;
      hown1 = (1.f - z1) * n1 + z1 * hown1;
      const unsigned short h0 = f2bf(hown0), h1 = f2bf(hown1);
      const unsigned short l0 = f2bf(hown0 - bf2f(h0)), l1 = f2bf(hown1 - bf2f(h1));
      const unsigned hi01 = (unsigned)h0 | ((unsigned)h1 << 16);
      const unsigned lo01 = (unsigned)l0 | ((unsigned)l1 << 16);
      char* hb = (char*)hbuf + wb * 114688;
      const int off = hswz(eb, 2 * (j0 + ec));
      astore32((unsigned*)(hb + off), hi01);
      astore32((unsigned*)(hb + off + 57344), lo01);
      orn_val = hi01;
    }

    // ---- P4: drain h stores only, arrive, ornn store under the poll, poll ----
    asm volatile("s_waitcnt vmcnt(0)" ::: "memory");
    __syncthreads();
    const unsigned tgt = (unsigned)(t + 1);
    if (tid == 0) astore32(arr + blockIdx.x, tgt);
    if (tid < 512) {
      *(unsigned*)(ornn + ((size_t)tl * 32 + eb) * H_ + j0 + ec) = orn_val;
    }
    if (wid == 0) {
      for (;;) {
        const unsigned v = (lane < NWG_SCAN) ? aload32(arr + lane) : tgt;
        if (__all(v >= tgt)) break;
        __builtin_amdgcn_s_sleep(1);
      }
    }
    __syncthreads();
  }
}

extern "C" void kernel_launch(void* const* d_in, const int* in_sizes, int n_in,
                              void* d_out, int out_size, void* d_ws, size_t ws_size,
                              hipStream_t stream) {
  (void)in_sizes; (void)n_in; (void)out_size;
  const int* sample = (const int*)d_in[0];
  const float* icnd = (const float*)d_in[1];
  const float* emb = (const float*)d_in[2];
  const float* wih = (const float*)d_in[3];
  const float* whh = (const float*)d_in[4];
  const float* bih = (const float*)d_in[5];
  const float* bhh = (const float*)d_in[6];
  const float* fc1w = (const float*)d_in[7];
  const float* fc1b = (const float*)d_in[8];
  const float* fc2w = (const float*)d_in[9];
  const float* fc2b = (const float*)d_in[10];
  float* out = (float*)d_out;
  char* ws = (char*)d_ws;

  size_t off = 0;
  auto alloc = [&](size_t bytes) {
    size_t o = off;
    off = (off + bytes + 255) & ~(size_t)255;
    return o;
  };
  const size_t o_arr = alloc(256);
  const size_t o_h = alloc((size_t)2 * 114688);  // swizzled h, 2 time slots
  const size_t zero_end = off;
  const size_t o_emb = alloc((size_t)O_ * EMB_ * 2);
  const size_t o_wih = alloc((size_t)G3_ * XD_ * 2);
  const size_t o_whh = alloc((size_t)G3_ * H_ * 2);
  const size_t o_f1w = alloc((size_t)H_ * H_ * 2);
  const size_t o_f2w = alloc((size_t)O_ * H_ * 2);
  const size_t head = off;

  int Tc = 512;
  while (Tc > 8) {
    size_t need = head + (size_t)Tc * 32 * G3_ * 4 + 2 * ((size_t)Tc * 32 * H_ * 2) + 4096;
    if (need <= ws_size) break;
    Tc >>= 1;
  }
  const size_t o_gat = alloc((size_t)Tc * 32 * G3_ * 4);
  const size_t o_orn = alloc((size_t)Tc * 32 * H_ * 2);
  const size_t o_hid = alloc((size_t)Tc * 32 * H_ * 2);
  (void)o_gat; (void)o_orn; (void)o_hid;

  unsigned short* embb = (unsigned short*)(ws + o_emb);
  unsigned short* wihb = (unsigned short*)(ws + o_wih);
  unsigned short* whhb = (unsigned short*)(ws + o_whh);
  unsigned short* f1wb = (unsigned short*)(ws + o_f1w);
  unsigned short* f2wb = (unsigned short*)(ws + o_f2w);
  float* gat = (float*)(ws + o_gat);
  unsigned short* orn = (unsigned short*)(ws + o_orn);
  unsigned short* hid = (unsigned short*)(ws + o_hid);
  unsigned long long* hbuf = (unsigned long long*)(ws + o_h);
  unsigned int* arr = (unsigned int*)(ws + o_arr);

  // zero arrival slots + h state (required every call: deterministic replays)
  (void)hipMemsetAsync(ws, 0, zero_end, stream);

  cvt_bf16<<<512, 256, 0, stream>>>(emb, embb, O_ * EMB_);
  cvt_bf16<<<1024, 256, 0, stream>>>(wih, wihb, G3_ * XD_);
  cvt_bf16<<<1024, 256, 0, stream>>>(whh, whhb, G3_ * H_);
  cvt_bf16<<<512, 256, 0, stream>>>(fc1w, f1wb, H_ * H_);
  cvt_bf16<<<512, 256, 0, stream>>>(fc2w, f2wb, O_ * H_);

  const int nch = T_FULL / Tc;
  const int M = Tc * 32;
  for (int c = 0; c < nch; ++c) {
    const int t0 = c * Tc;
    gemm_bf16<0><<<dim3(G3_ / 128, M / 128), 256, 0, stream>>>(
        nullptr, sample, icnd, embb, wihb, bih, gat, nullptr, t0);
    scan_gru<<<NWG_SCAN, THR_SCAN, 0, stream>>>(gat, whhb, bhh, hbuf, orn, arr, t0, Tc);
    gemm_bf16<1><<<dim3(H_ / 128, M / 128), 256, 0, stream>>>(
        orn, nullptr, nullptr, nullptr, f1wb, fc1b, nullptr, hid, t0);
    gemm_bf16<2><<<dim3(O_ / 128, M / 128), 256, 0, stream>>>(
        hid, nullptr, nullptr, nullptr, f2wb, fc2b, out, nullptr, t0);
  }
}